// Round 12
// baseline (190.160 us; speedup 1.0000x reference)
//
#include <hip/hip_runtime.h>

// Problem constants (from reference; all fp32 I/O)
#define NVIEW 5
#define NB    128000          // NBINS = 80*80*20
#define CF    32
#define HID   256
#define KA    96              // padded K for the MLP GEMM
#define IMG_HW 262144         // 512*512
#define FT_HW  16384          // 128*128

typedef __attribute__((ext_vector_type(8))) short short8;   // 8 bf16 (4 VGPRs)
typedef __attribute__((ext_vector_type(4))) float f32x4;    // MFMA accumulator

__device__ __forceinline__ unsigned int f2bf(float f) {
    unsigned int u = __float_as_uint(f);
    return (u + 0x7fffu + ((u >> 16) & 1u)) >> 16;   // RTNE, low 16 bits
}
__device__ __forceinline__ unsigned int pk(float a, float b) {
    return f2bf(a) | (f2bf(b) << 16);
}
__device__ __forceinline__ float b2f_lo(unsigned int u) { return __uint_as_float(u << 16); }
__device__ __forceinline__ float b2f_hi(unsigned int u) { return __uint_as_float(u & 0xffff0000u); }

// A-row layout (96 shorts per row = 2n+b), built by lane halves:
//  half0 (shorts 0..47):  pts(3) mi(3) mf ch0..15 | vi(3) pad vf ch0..15 pad(6)
//  half1 (shorts 48..95): mf ch16..31 (16) vf ch16..31 (16) pad(16)
// mapk: A-row k -> original W1 row i (73-dim input), -1 = zero pad.
__device__ __forceinline__ int mapk(int k) {
    if (k < 22) return k;          // pts + mean img + mean feat0..15
    if (k < 25) return k + 16;     // var img
    if (k == 25) return -1;
    if (k < 42) return k + 15;     // var feat0..15
    if (k < 48) return -1;
    if (k < 64) return k - 26;     // mean feat16..31
    if (k < 80) return k - 7;      // var feat16..31
    return -1;
}

// ---------------------------------------------------------------------------
// Kernel 1: ALL preprocessing in one launch (blockIdx-range split).
//  [0,1280):    repack imgs (4 px/thread) -> [V][512][512][8] uint8 fixed-pt
//               pixel = b0c0,b0c1,b0c2,pad | b1c0,b1c1,b1c2,pad (8B = uint2)
//               u8 x255 quantization: max err 0.002 (better than bf16 on [0,1])
//  [1280,2560): repack feats -> [V][128][128][2][32] bf16 (LDS tile)
//  [2560,2608): build W1 B-fragment image + b1|W2|b2 staging
// ---------------------------------------------------------------------------
__global__ __launch_bounds__(256) void prep(
    const float* __restrict__ imgs, const float* __restrict__ feats,
    const float* __restrict__ W1, const float* __restrict__ b1,
    const float* __restrict__ W2, const float* __restrict__ b2,
    uint2* __restrict__ imgsP, uint4* __restrict__ featsP,
    unsigned int* __restrict__ Bfrag, float* __restrict__ bw)
{
    const int bidx = blockIdx.x;
    const int t = threadIdx.x;
    if (bidx < 1280) {
        // ---- images: 4 consecutive pixels per thread, u8 quantize ----
        int gid = bidx * 256 + t;               // 327,680
        int v   = gid >> 16;                    // 65536 pixel-quads per view
        int px  = (gid & 65535) * 4;
        const float* base = imgs + (size_t)v * 6 * IMG_HW + px;
        float4 pl[6];
        #pragma unroll
        for (int p = 0; p < 6; p++)
            pl[p] = *(const float4*)(base + (size_t)p * IMG_HW);
        uint2 o[4];
        #pragma unroll
        for (int i = 0; i < 4; i++) {
            unsigned int c[6];
            #pragma unroll
            for (int p = 0; p < 6; p++)
                c[p] = (unsigned int)fminf(((const float*)&pl[p])[i] * 255.f + 0.5f, 255.f);
            o[i].x = c[0] | (c[1] << 8) | (c[2] << 16);
            o[i].y = c[3] | (c[4] << 8) | (c[5] << 16);
        }
        uint4* dst = (uint4*)(imgsP + (size_t)v * IMG_HW + px);
        dst[0] = make_uint4(o[0].x, o[0].y, o[1].x, o[1].y);
        dst[1] = make_uint4(o[2].x, o[2].y, o[3].x, o[3].y);
    } else if (bidx < 2560) {
        // ---- features via LDS tile ----
        __shared__ unsigned short tile[64][65];
        const int pixbase = (bidx - 1280) * 64;
        const int v   = pixbase >> 14;
        const int rem = pixbase & 16383;
        {
            const int p = t & 63;
            const int s = t >> 6;
            #pragma unroll
            for (int it = 0; it < 16; it++) {
                int plane = it * 4 + s;         // = b*32 + ch
                tile[plane][p] =
                    (unsigned short)f2bf(feats[((size_t)v * 64 + plane) * FT_HW + rem + p]);
            }
        }
        __syncthreads();
        {
            const int q = t & 7;
            #pragma unroll
            for (int it = 0; it < 2; it++) {
                int p = it * 32 + (t >> 3);
                uint4 o;
                o.x = (unsigned)tile[q * 8 + 0][p] | ((unsigned)tile[q * 8 + 1][p] << 16);
                o.y = (unsigned)tile[q * 8 + 2][p] | ((unsigned)tile[q * 8 + 3][p] << 16);
                o.z = (unsigned)tile[q * 8 + 4][p] | ((unsigned)tile[q * 8 + 5][p] << 16);
                o.w = (unsigned)tile[q * 8 + 6][p] | ((unsigned)tile[q * 8 + 7][p] << 16);
                featsP[(size_t)(pixbase + p) * 8 + q] = o;
            }
        }
    } else {
        // ---- W1 fragment image (mapk-permuted, bf16 pairs) ----
        int e = (bidx - 2560) * 256 + t;        // [0, 12288)
        int ju = e & 3;
        int nn = (e >> 2) & 255;
        int o  = e >> 10;
        int k0 = o * 8 + ju * 2;
        int i0 = mapk(k0), i1 = mapk(k0 + 1);
        float f0 = (i0 >= 0) ? W1[i0 * 256 + nn] : 0.f;
        float f1 = (i1 >= 0) ? W1[i1 * 256 + nn] : 0.f;
        Bfrag[e] = pk(f0, f1);
        if (e < 256)       bw[e] = b1[e];
        else if (e < 512)  bw[e] = W2[e - 256];
        else if (e == 512) bw[e] = b2[0];
    }
}

// ---------------------------------------------------------------------------
// Kernel 2: FUSED gather + MLP — round-7 structure (best fused: 97.4us,
// single barrier, B staged ONCE in 48KB LDS, (256,2), zero spill) with the
// ONLY change being u8 images. Rounds 8-11 proved: forced (256,3) spills
// 60-170MB; B-quartering's 6 extra barriers + serialized restages cost ~40us
// of exposed latency. One block = 64 points x 4 lanes = 128 GEMM rows.
// mfma: A[m=lane&15][k=quad*8+j], B[k][n=lane&15], C: col=lane&15,
// row=quad*4+reg  [verified layouts, learn_hip m89]
// ---------------------------------------------------------------------------
#define AROW 13   // uint4s per LDS A-row (12 data + 1 pad for bank spread)

__global__ __launch_bounds__(256, 2) void fused_gather_mlp(
    const uint2* __restrict__ imgsP,            // [V][512][512] u8x8
    const unsigned short* __restrict__ featsP,  // [V][128][128][2][32] bf16
    const float* __restrict__ grid,             // [V][NB][2]
    const float* __restrict__ points,           // [NB][3]
    const unsigned int*   __restrict__ Bfrag,   // [12288] prebuilt fragments
    const float*          __restrict__ bw,      // b1(256) | W2(256) | b2(1)
    float* __restrict__ out)                    // [256000] = [B][NB]
{
    __shared__ unsigned int Bl[12288];          // 48 KB: full B
    __shared__ uint4 As4[128 * AROW];           // 26.6 KB
    __shared__ float b1s[HID];
    __shared__ float W2s[HID];

    const int tid = threadIdx.x;

    // stage B fragments + biases (coalesced; Bfrag is L2-hot, 48 KB)
    {
        const uint4* src = (const uint4*)Bfrag;
        uint4* dst = (uint4*)Bl;
        #pragma unroll
        for (int i = 0; i < 12; i++) dst[i * 256 + tid] = src[i * 256 + tid];
        b1s[tid] = bw[tid];
        W2s[tid] = bw[256 + tid];
    }
    const float b2v = bw[512];

    // ================= gather phase =================
    const int n    = blockIdx.x * 64 + (tid >> 2);
    const int b    = (tid >> 1) & 1;
    const int half = tid & 1;

    float sumf[16], ssqf[16];
    #pragma unroll
    for (int c = 0; c < 16; c++) { sumf[c] = 0.f; ssqf[c] = 0.f; }
    float si0 = 0.f, si1 = 0.f, si2 = 0.f;      // 255-scaled img sums
    float qi0 = 0.f, qi1 = 0.f, qi2 = 0.f;
    float p0 = 0.f, p1 = 0.f, p2 = 0.f;
    if (half == 0) {
        p0 = points[n * 3 + 0];
        p1 = points[n * 3 + 1];
        p2 = points[n * 3 + 2];
    }

    #pragma unroll
    for (int v = 0; v < NVIEW; v++) {
        const float2 g = ((const float2*)grid)[v * NB + n];
        const float gx = g.x, gy = g.y;

        // ---- image sample (half0 lanes only): 8B per corner, u8 decode ----
        if (half == 0) {
            float ix = (gx + 1.f) * 0.5f * 511.f;
            float iy = (gy + 1.f) * 0.5f * 511.f;
            float x0f = floorf(ix), y0f = floorf(iy);
            float x1f = x0f + 1.f, y1f = y0f + 1.f;
            float wx1 = ix - x0f, wx0 = 1.f - wx1;
            float wy1 = iy - y0f, wy0 = 1.f - wy1;
            float vi0 = 0.f, vi1 = 0.f, vi2 = 0.f;
            const uint2* base = imgsP + (size_t)v * IMG_HW;
            #pragma unroll
            for (int k = 0; k < 4; k++) {
                float xf = (k & 1) ? x1f : x0f;
                float yf = (k >> 1) ? y1f : y0f;
                float w  = ((k & 1) ? wx1 : wx0) * ((k >> 1) ? wy1 : wy0);
                float vd = (xf >= 0.f && xf <= 511.f && yf >= 0.f && yf <= 511.f) ? 1.f : 0.f;
                w *= vd;
                int xi = (int)fminf(fmaxf(xf, 0.f), 511.f);
                int yi = (int)fminf(fmaxf(yf, 0.f), 511.f);
                uint2 iv = base[yi * 512 + xi];
                unsigned int sel = b ? iv.y : iv.x;
                vi0 += w * (float)(sel & 255u);
                vi1 += w * (float)((sel >> 8) & 255u);
                vi2 += w * (float)((sel >> 16) & 255u);
            }
            si0 += vi0; qi0 += vi0 * vi0;
            si1 += vi1; qi1 += vi1 * vi1;
            si2 += vi2; qi2 += vi2 * vi2;
        }

        // ---- feature sample: 32B per corner per lane (contiguous x4 lanes) ----
        {
            float ix = (gx + 1.f) * 0.5f * 127.f;
            float iy = (gy + 1.f) * 0.5f * 127.f;
            float x0f = floorf(ix), y0f = floorf(iy);
            float x1f = x0f + 1.f, y1f = y0f + 1.f;
            float wx1 = ix - x0f, wx0 = 1.f - wx1;
            float wy1 = iy - y0f, wy0 = 1.f - wy1;
            const unsigned short* fb =
                featsP + ((size_t)v * FT_HW) * 64 + b * 32 + half * 16;
            float val[16];
            #pragma unroll
            for (int c = 0; c < 16; c++) val[c] = 0.f;
            #pragma unroll
            for (int k = 0; k < 4; k++) {
                float xf = (k & 1) ? x1f : x0f;
                float yf = (k >> 1) ? y1f : y0f;
                float w  = ((k & 1) ? wx1 : wx0) * ((k >> 1) ? wy1 : wy0);
                float vd = (xf >= 0.f && xf <= 127.f && yf >= 0.f && yf <= 127.f) ? 1.f : 0.f;
                w *= vd;
                int xi = (int)fminf(fmaxf(xf, 0.f), 127.f);
                int yi = (int)fminf(fmaxf(yf, 0.f), 127.f);
                const uint4* p = (const uint4*)(fb + (size_t)(yi * 128 + xi) * 64);
                #pragma unroll
                for (int q = 0; q < 2; q++) {
                    uint4 f4 = p[q];
                    val[q * 8 + 0] += w * b2f_lo(f4.x);
                    val[q * 8 + 1] += w * b2f_hi(f4.x);
                    val[q * 8 + 2] += w * b2f_lo(f4.y);
                    val[q * 8 + 3] += w * b2f_hi(f4.y);
                    val[q * 8 + 4] += w * b2f_lo(f4.z);
                    val[q * 8 + 5] += w * b2f_hi(f4.z);
                    val[q * 8 + 6] += w * b2f_lo(f4.w);
                    val[q * 8 + 7] += w * b2f_hi(f4.w);
                }
            }
            #pragma unroll
            for (int c = 0; c < 16; c++) {
                sumf[c] += val[c];
                ssqf[c] += val[c] * val[c];
            }
        }
    }

    // finalize mean / exp(-var)  (img sums rescaled from 255-space here)
    #pragma unroll
    for (int c = 0; c < 16; c++) {
        float m = sumf[c] * 0.2f;
        float q = ssqf[c] * 0.2f - m * m;
        sumf[c] = m;
        ssqf[c] = expf(-q);
    }
    const float s1 = 0.2f * (1.f / 255.f);
    const float s2 = 0.2f * (1.f / 65025.f);
    float mi0 = si0 * s1, mi1 = si1 * s1, mi2 = si2 * s1;
    float ei0 = expf(-(qi0 * s2 - mi0 * mi0));
    float ei1 = expf(-(qi1 * s2 - mi1 * mi1));
    float ei2 = expf(-(qi2 * s2 - mi2 * mi2));

    unsigned int u[24];
    if (half == 0) {
        u[0] = pk(p0, p1);
        u[1] = pk(p2, mi0);
        u[2] = pk(mi1, mi2);
        #pragma unroll
        for (int j = 0; j < 8; j++) u[3 + j] = pk(sumf[2 * j], sumf[2 * j + 1]);
        u[11] = pk(ei0, ei1);
        u[12] = pk(ei2, 0.f);
        #pragma unroll
        for (int j = 0; j < 8; j++) u[13 + j] = pk(ssqf[2 * j], ssqf[2 * j + 1]);
        u[21] = 0u; u[22] = 0u; u[23] = 0u;
    } else {
        #pragma unroll
        for (int j = 0; j < 8; j++) u[j]     = pk(sumf[2 * j], sumf[2 * j + 1]);
        #pragma unroll
        for (int j = 0; j < 8; j++) u[8 + j] = pk(ssqf[2 * j], ssqf[2 * j + 1]);
        #pragma unroll
        for (int j = 16; j < 24; j++) u[j] = 0u;
    }

    // write my 96B half-row to LDS: local row = tid>>1 in [0,128)
    {
        uint4* arow = &As4[(tid >> 1) * AROW + half * 6];
        #pragma unroll
        for (int i = 0; i < 6; i++)
            arow[i] = make_uint4(u[4 * i], u[4 * i + 1], u[4 * i + 2], u[4 * i + 3]);
    }
    __syncthreads();   // (1) As4 + Bl + biases all visible — the ONLY barrier

    // ================= GEMM phase =================
    const int w    = tid >> 6;
    const int lane = tid & 63;
    const int col  = lane & 15;
    const int quad = lane >> 4;
    const long rowbase = (long)blockIdx.x * 128 + w * 32;

    f32x4 acc[2][16];
    #pragma unroll
    for (int m = 0; m < 2; m++)
        #pragma unroll
        for (int t = 0; t < 16; t++)
            acc[m][t] = (f32x4){0.f, 0.f, 0.f, 0.f};

    const unsigned int* bp = Bl + (quad * 256 + col) * 4;

    #pragma unroll
    for (int s = 0; s < 3; s++) {
        short8 af0 = *(const short8*)&As4[(w * 32 + col)      * AROW + s * 4 + quad];
        short8 af1 = *(const short8*)&As4[(w * 32 + 16 + col) * AROW + s * 4 + quad];
        #pragma unroll
        for (int t = 0; t < 16; t++) {
            short8 bf = *(const short8*)(bp + s * 4096 + t * 64);
            acc[0][t] = __builtin_amdgcn_mfma_f32_16x16x32_bf16(af0, bf, acc[0][t], 0, 0, 0);
            acc[1][t] = __builtin_amdgcn_mfma_f32_16x16x32_bf16(af1, bf, acc[1][t], 0, 0, 0);
        }
    }

    // epilogue: +b1, relu, dot W2, cross-col reduce, softplus -> alpha
    float pm[2][4] = {{0.f, 0.f, 0.f, 0.f}, {0.f, 0.f, 0.f, 0.f}};
    #pragma unroll
    for (int t = 0; t < 16; t++) {
        float b1v = b1s[t * 16 + col];
        float w2v = W2s[t * 16 + col];
        #pragma unroll
        for (int m = 0; m < 2; m++)
            #pragma unroll
            for (int r = 0; r < 4; r++) {
                float h = fmaxf(acc[m][t][r] + b1v, 0.f);
                pm[m][r] += h * w2v;
            }
    }
    #pragma unroll
    for (int m = 0; m < 2; m++)
        #pragma unroll
        for (int r = 0; r < 4; r++) {
            float p = pm[m][r];
            p += __shfl_xor(p, 1);
            p += __shfl_xor(p, 2);
            p += __shfl_xor(p, 4);
            p += __shfl_xor(p, 8);
            pm[m][r] = p;
        }

    if (col == 0) {
        #pragma unroll
        for (int m = 0; m < 2; m++)
            #pragma unroll
            for (int r = 0; r < 4; r++) {
                float x  = pm[m][r] + b2v;
                float sp = fmaxf(x, 0.f) + log1pf(expf(-fabsf(x)));  // softplus
                float alpha = -expm1f(-sp);                          // 1 - exp(-sp)
                long row = rowbase + m * 16 + quad * 4 + r;          // = 2n + b
                out[(row & 1) * (long)NB + (row >> 1)] = alpha;
            }
    }
}

extern "C" void kernel_launch(void* const* d_in, const int* in_sizes, int n_in,
                              void* d_out, int out_size, void* d_ws, size_t ws_size,
                              hipStream_t stream) {
    const float* imgs   = (const float*)d_in[0];
    const float* feats  = (const float*)d_in[1];
    const float* grid   = (const float*)d_in[2];
    const float* points = (const float*)d_in[3];
    const float* W1     = (const float*)d_in[4];
    const float* b1     = (const float*)d_in[5];
    const float* W2     = (const float*)d_in[6];
    const float* b2     = (const float*)d_in[7];
    float* out = (float*)d_out;

    // workspace: imgsP(u8) 10.49MB | featsP 10.49MB | Bfrag 48KB | bw 2.05KB
    uint2*          imgsP  = (uint2*)d_ws;
    unsigned short* featsP = (unsigned short*)(imgsP + (size_t)NVIEW * IMG_HW);
    unsigned int*   Bfrag  = (unsigned int*)(featsP + (size_t)NVIEW * FT_HW * 64);
    float*          bwbuf  = (float*)(Bfrag + 12288);

    prep<<<dim3(2608), dim3(256), 0, stream>>>(
        imgs, feats, W1, b1, W2, b2,
        imgsP, (uint4*)featsP, Bfrag, bwbuf);
    fused_gather_mlp<<<dim3(2000), dim3(256), 0, stream>>>(
        imgsP, featsP, grid, points, Bfrag, bwbuf, out);
}

// Round 13
// 186.254 us; speedup vs baseline: 1.0210x; 1.0210x over previous
//
#include <hip/hip_runtime.h>

// Problem constants (from reference; all fp32 I/O)
#define NVIEW 5
#define NB    128000          // NBINS = 80*80*20
#define CF    32
#define HID   256
#define KA    96              // padded K for the MLP GEMM
#define IMG_HW 262144         // 512*512
#define FT_HW  16384          // 128*128

typedef __attribute__((ext_vector_type(8))) short short8;   // 8 bf16 (4 VGPRs)
typedef __attribute__((ext_vector_type(4))) float f32x4;    // MFMA accumulator

__device__ __forceinline__ unsigned int f2bf(float f) {
    unsigned int u = __float_as_uint(f);
    return (u + 0x7fffu + ((u >> 16) & 1u)) >> 16;   // RTNE, low 16 bits
}
__device__ __forceinline__ unsigned int pk(float a, float b) {
    return f2bf(a) | (f2bf(b) << 16);
}
__device__ __forceinline__ float b2f_lo(unsigned int u) { return __uint_as_float(u << 16); }
__device__ __forceinline__ float b2f_hi(unsigned int u) { return __uint_as_float(u & 0xffff0000u); }

// A-row layout (96 shorts per row = 2n+b), built by lane halves:
//  half0 (shorts 0..47):  pts(3) mi(3) mf ch0..15 | vi(3) pad vf ch0..15 pad(6)
//  half1 (shorts 48..95): mf ch16..31 (16) vf ch16..31 (16) pad(16)
// mapk: A-row k -> original W1 row i (73-dim input), -1 = zero pad.
__device__ __forceinline__ int mapk(int k) {
    if (k < 22) return k;          // pts + mean img + mean feat0..15
    if (k < 25) return k + 16;     // var img
    if (k == 25) return -1;
    if (k < 42) return k + 15;     // var feat0..15
    if (k < 48) return -1;
    if (k < 64) return k - 26;     // mean feat16..31
    if (k < 80) return k - 7;      // var feat16..31
    return -1;
}

// ---------------------------------------------------------------------------
// Kernel 1: ALL preprocessing in one launch (blockIdx-range split).
//  [0,1280):    repack imgs (4 px/thread) -> [V][512][512][8] uint8 fixed-pt
//  [1280,2560): repack feats -> [V][128][128][2][32] bf16 (LDS tile)
//  [2560,2608): build W1 B-fragment image + b1|W2|b2 staging
// ---------------------------------------------------------------------------
__global__ __launch_bounds__(256) void prep(
    const float* __restrict__ imgs, const float* __restrict__ feats,
    const float* __restrict__ W1, const float* __restrict__ b1,
    const float* __restrict__ W2, const float* __restrict__ b2,
    uint2* __restrict__ imgsP, uint4* __restrict__ featsP,
    unsigned int* __restrict__ Bfrag, float* __restrict__ bw)
{
    const int bidx = blockIdx.x;
    const int t = threadIdx.x;
    if (bidx < 1280) {
        // ---- images: 4 consecutive pixels per thread, u8 quantize ----
        int gid = bidx * 256 + t;               // 327,680
        int v   = gid >> 16;                    // 65536 pixel-quads per view
        int px  = (gid & 65535) * 4;
        const float* base = imgs + (size_t)v * 6 * IMG_HW + px;
        float4 pl[6];
        #pragma unroll
        for (int p = 0; p < 6; p++)
            pl[p] = *(const float4*)(base + (size_t)p * IMG_HW);
        uint2 o[4];
        #pragma unroll
        for (int i = 0; i < 4; i++) {
            unsigned int c[6];
            #pragma unroll
            for (int p = 0; p < 6; p++)
                c[p] = (unsigned int)fminf(((const float*)&pl[p])[i] * 255.f + 0.5f, 255.f);
            o[i].x = c[0] | (c[1] << 8) | (c[2] << 16);
            o[i].y = c[3] | (c[4] << 8) | (c[5] << 16);
        }
        uint4* dst = (uint4*)(imgsP + (size_t)v * IMG_HW + px);
        dst[0] = make_uint4(o[0].x, o[0].y, o[1].x, o[1].y);
        dst[1] = make_uint4(o[2].x, o[2].y, o[3].x, o[3].y);
    } else if (bidx < 2560) {
        // ---- features via LDS tile ----
        __shared__ unsigned short tile[64][65];
        const int pixbase = (bidx - 1280) * 64;
        const int v   = pixbase >> 14;
        const int rem = pixbase & 16383;
        {
            const int p = t & 63;
            const int s = t >> 6;
            #pragma unroll
            for (int it = 0; it < 16; it++) {
                int plane = it * 4 + s;         // = b*32 + ch
                tile[plane][p] =
                    (unsigned short)f2bf(feats[((size_t)v * 64 + plane) * FT_HW + rem + p]);
            }
        }
        __syncthreads();
        {
            const int q = t & 7;
            #pragma unroll
            for (int it = 0; it < 2; it++) {
                int p = it * 32 + (t >> 3);
                uint4 o;
                o.x = (unsigned)tile[q * 8 + 0][p] | ((unsigned)tile[q * 8 + 1][p] << 16);
                o.y = (unsigned)tile[q * 8 + 2][p] | ((unsigned)tile[q * 8 + 3][p] << 16);
                o.z = (unsigned)tile[q * 8 + 4][p] | ((unsigned)tile[q * 8 + 5][p] << 16);
                o.w = (unsigned)tile[q * 8 + 6][p] | ((unsigned)tile[q * 8 + 7][p] << 16);
                featsP[(size_t)(pixbase + p) * 8 + q] = o;
            }
        }
    } else {
        // ---- W1 fragment image (mapk-permuted, bf16 pairs) ----
        int e = (bidx - 2560) * 256 + t;        // [0, 12288)
        int ju = e & 3;
        int nn = (e >> 2) & 255;
        int o  = e >> 10;
        int k0 = o * 8 + ju * 2;
        int i0 = mapk(k0), i1 = mapk(k0 + 1);
        float f0 = (i0 >= 0) ? W1[i0 * 256 + nn] : 0.f;
        float f1 = (i1 >= 0) ? W1[i1 * 256 + nn] : 0.f;
        Bfrag[e] = pk(f0, f1);
        if (e < 256)       bw[e] = b1[e];
        else if (e < 512)  bw[e] = W2[e - 256];
        else if (e == 512) bw[e] = b2[0];
    }
}

// ---------------------------------------------------------------------------
// Kernel 2: FUSED gather + MLP with LDS TIME-SHARING. Key insight: the A
// exchange is INTRA-WAVE (wave w's lanes produce rows 32w..32w+31 = exactly
// the rows wave w's GEMM consumes), so A goes through LDS with NO barrier
// (same-wave ds_write -> ds_read, lgkmcnt-ordered), each wave pulls its af
// fragments into registers, THEN the same 48KB buffer is overwritten with B.
// LDS = 48 + 2 = 50KB -> 3 blocks/CU (was 77.8KB -> 2). acc split [2][8]
// via h-loop over the fully-resident B (no restaging, only 2 barriers).
// mfma: A[m=lane&15][k=quad*8+j], B[k][n=lane&15], C: col=lane&15,
// row=quad*4+reg  [verified layouts, learn_hip m89]
// ---------------------------------------------------------------------------
#define AROW 13   // uint4s per LDS A-row (12 data + 1 pad for bank spread)

__global__ __launch_bounds__(256, 2) void fused_gather_mlp(
    const uint2* __restrict__ imgsP,            // [V][512][512] u8x8
    const unsigned short* __restrict__ featsP,  // [V][128][128][2][32] bf16
    const float* __restrict__ grid,             // [V][NB][2]
    const float* __restrict__ points,           // [NB][3]
    const unsigned int*   __restrict__ Bfrag,   // [12288] prebuilt fragments
    const float*          __restrict__ bw,      // b1(256) | W2(256) | b2(1)
    float* __restrict__ out)                    // [256000] = [B][NB]
{
    __shared__ unsigned int Lds[12288];         // 48 KB: A-tile, then B
    __shared__ float b1s[HID];
    __shared__ float W2s[HID];

    const int tid = threadIdx.x;
    b1s[tid] = bw[tid];
    W2s[tid] = bw[256 + tid];
    const float b2v = bw[512];

    // ================= gather phase =================
    const int n    = blockIdx.x * 64 + (tid >> 2);
    const int b    = (tid >> 1) & 1;
    const int half = tid & 1;

    float sumf[16], ssqf[16];
    #pragma unroll
    for (int c = 0; c < 16; c++) { sumf[c] = 0.f; ssqf[c] = 0.f; }
    float si0 = 0.f, si1 = 0.f, si2 = 0.f;      // 255-scaled img sums
    float qi0 = 0.f, qi1 = 0.f, qi2 = 0.f;
    float p0 = 0.f, p1 = 0.f, p2 = 0.f;
    if (half == 0) {
        p0 = points[n * 3 + 0];
        p1 = points[n * 3 + 1];
        p2 = points[n * 3 + 2];
    }

    #pragma unroll
    for (int v = 0; v < NVIEW; v++) {
        const float2 g = ((const float2*)grid)[v * NB + n];
        const float gx = g.x, gy = g.y;

        // ---- image sample (half0 lanes only): 8B per corner, u8 decode ----
        if (half == 0) {
            float ix = (gx + 1.f) * 0.5f * 511.f;
            float iy = (gy + 1.f) * 0.5f * 511.f;
            float x0f = floorf(ix), y0f = floorf(iy);
            float x1f = x0f + 1.f, y1f = y0f + 1.f;
            float wx1 = ix - x0f, wx0 = 1.f - wx1;
            float wy1 = iy - y0f, wy0 = 1.f - wy1;
            float vi0 = 0.f, vi1 = 0.f, vi2 = 0.f;
            const uint2* base = imgsP + (size_t)v * IMG_HW;
            #pragma unroll
            for (int k = 0; k < 4; k++) {
                float xf = (k & 1) ? x1f : x0f;
                float yf = (k >> 1) ? y1f : y0f;
                float w  = ((k & 1) ? wx1 : wx0) * ((k >> 1) ? wy1 : wy0);
                float vd = (xf >= 0.f && xf <= 511.f && yf >= 0.f && yf <= 511.f) ? 1.f : 0.f;
                w *= vd;
                int xi = (int)fminf(fmaxf(xf, 0.f), 511.f);
                int yi = (int)fminf(fmaxf(yf, 0.f), 511.f);
                uint2 iv = base[yi * 512 + xi];
                unsigned int sel = b ? iv.y : iv.x;
                vi0 += w * (float)(sel & 255u);
                vi1 += w * (float)((sel >> 8) & 255u);
                vi2 += w * (float)((sel >> 16) & 255u);
            }
            si0 += vi0; qi0 += vi0 * vi0;
            si1 += vi1; qi1 += vi1 * vi1;
            si2 += vi2; qi2 += vi2 * vi2;
        }

        // ---- feature sample: 32B per corner per lane (contiguous x4 lanes) ----
        {
            float ix = (gx + 1.f) * 0.5f * 127.f;
            float iy = (gy + 1.f) * 0.5f * 127.f;
            float x0f = floorf(ix), y0f = floorf(iy);
            float x1f = x0f + 1.f, y1f = y0f + 1.f;
            float wx1 = ix - x0f, wx0 = 1.f - wx1;
            float wy1 = iy - y0f, wy0 = 1.f - wy1;
            const unsigned short* fb =
                featsP + ((size_t)v * FT_HW) * 64 + b * 32 + half * 16;
            float val[16];
            #pragma unroll
            for (int c = 0; c < 16; c++) val[c] = 0.f;
            #pragma unroll
            for (int k = 0; k < 4; k++) {
                float xf = (k & 1) ? x1f : x0f;
                float yf = (k >> 1) ? y1f : y0f;
                float w  = ((k & 1) ? wx1 : wx0) * ((k >> 1) ? wy1 : wy0);
                float vd = (xf >= 0.f && xf <= 127.f && yf >= 0.f && yf <= 127.f) ? 1.f : 0.f;
                w *= vd;
                int xi = (int)fminf(fmaxf(xf, 0.f), 127.f);
                int yi = (int)fminf(fmaxf(yf, 0.f), 127.f);
                const uint4* p = (const uint4*)(fb + (size_t)(yi * 128 + xi) * 64);
                #pragma unroll
                for (int q = 0; q < 2; q++) {
                    uint4 f4 = p[q];
                    val[q * 8 + 0] += w * b2f_lo(f4.x);
                    val[q * 8 + 1] += w * b2f_hi(f4.x);
                    val[q * 8 + 2] += w * b2f_lo(f4.y);
                    val[q * 8 + 3] += w * b2f_hi(f4.y);
                    val[q * 8 + 4] += w * b2f_lo(f4.z);
                    val[q * 8 + 5] += w * b2f_hi(f4.z);
                    val[q * 8 + 6] += w * b2f_lo(f4.w);
                    val[q * 8 + 7] += w * b2f_hi(f4.w);
                }
            }
            #pragma unroll
            for (int c = 0; c < 16; c++) {
                sumf[c] += val[c];
                ssqf[c] += val[c] * val[c];
            }
        }
    }

    // finalize mean / exp(-var)  (img sums rescaled from 255-space here)
    #pragma unroll
    for (int c = 0; c < 16; c++) {
        float m = sumf[c] * 0.2f;
        float q = ssqf[c] * 0.2f - m * m;
        sumf[c] = m;
        ssqf[c] = expf(-q);
    }
    const float s1 = 0.2f * (1.f / 255.f);
    const float s2 = 0.2f * (1.f / 65025.f);
    float mi0 = si0 * s1, mi1 = si1 * s1, mi2 = si2 * s1;
    float ei0 = expf(-(qi0 * s2 - mi0 * mi0));
    float ei1 = expf(-(qi1 * s2 - mi1 * mi1));
    float ei2 = expf(-(qi2 * s2 - mi2 * mi2));

    unsigned int u[24];
    if (half == 0) {
        u[0] = pk(p0, p1);
        u[1] = pk(p2, mi0);
        u[2] = pk(mi1, mi2);
        #pragma unroll
        for (int j = 0; j < 8; j++) u[3 + j] = pk(sumf[2 * j], sumf[2 * j + 1]);
        u[11] = pk(ei0, ei1);
        u[12] = pk(ei2, 0.f);
        #pragma unroll
        for (int j = 0; j < 8; j++) u[13 + j] = pk(ssqf[2 * j], ssqf[2 * j + 1]);
        u[21] = 0u; u[22] = 0u; u[23] = 0u;
    } else {
        #pragma unroll
        for (int j = 0; j < 8; j++) u[j]     = pk(sumf[2 * j], sumf[2 * j + 1]);
        #pragma unroll
        for (int j = 0; j < 8; j++) u[8 + j] = pk(ssqf[2 * j], ssqf[2 * j + 1]);
        #pragma unroll
        for (int j = 16; j < 24; j++) u[j] = 0u;
    }

    // ---- intra-wave A exchange through Lds (NO barrier needed) ----
    // write my 96B half-row: local row = tid>>1 (rows 32w..32w+31 belong to
    // wave w); wave w's GEMM reads rows 32w+col / 32w+16+col — same wave.
    uint4* As4 = (uint4*)Lds;
    {
        uint4* arow = &As4[(tid >> 1) * AROW + half * 6];
        #pragma unroll
        for (int i = 0; i < 6; i++)
            arow[i] = make_uint4(u[4 * i], u[4 * i + 1], u[4 * i + 2], u[4 * i + 3]);
    }

    const int w    = tid >> 6;
    const int lane = tid & 63;
    const int col  = lane & 15;
    const int quad = lane >> 4;
    const long rowbase = (long)blockIdx.x * 128 + w * 32;

    // pull A fragments into registers (lgkmcnt-ordered vs the writes above)
    short8 af[2][3];
    #pragma unroll
    for (int s = 0; s < 3; s++) {
        af[0][s] = *(const short8*)&As4[(w * 32 + col)      * AROW + s * 4 + quad];
        af[1][s] = *(const short8*)&As4[(w * 32 + 16 + col) * AROW + s * 4 + quad];
    }

    __syncthreads();   // (1) all waves done with the A region

    // stage FULL B over the same buffer (48KB, coalesced from L2-hot Bfrag)
    {
        const uint4* src = (const uint4*)Bfrag;
        uint4* dst = (uint4*)Lds;
        #pragma unroll
        for (int i = 0; i < 12; i++) dst[i * 256 + tid] = src[i * 256 + tid];
    }
    __syncthreads();   // (2) B + b1s/W2s visible

    // ================= GEMM phase =================
    const unsigned int* bp = Lds + (quad * 256 + col) * 4;

    float pm[2][4] = {{0.f, 0.f, 0.f, 0.f}, {0.f, 0.f, 0.f, 0.f}};
    #pragma unroll
    for (int h = 0; h < 2; h++) {
        f32x4 acc[2][8];
        #pragma unroll
        for (int m = 0; m < 2; m++)
            #pragma unroll
            for (int t = 0; t < 8; t++)
                acc[m][t] = (f32x4){0.f, 0.f, 0.f, 0.f};

        #pragma unroll
        for (int s = 0; s < 3; s++) {
            #pragma unroll
            for (int t = 0; t < 8; t++) {
                short8 bf = *(const short8*)(bp + s * 4096 + (h * 8 + t) * 64);
                acc[0][t] = __builtin_amdgcn_mfma_f32_16x16x32_bf16(af[0][s], bf, acc[0][t], 0, 0, 0);
                acc[1][t] = __builtin_amdgcn_mfma_f32_16x16x32_bf16(af[1][s], bf, acc[1][t], 0, 0, 0);
            }
        }

        // epilogue partials: +b1, relu, dot W2 over this half's 128 cols
        #pragma unroll
        for (int t = 0; t < 8; t++) {
            int j = h * 128 + t * 16 + col;
            float b1v = b1s[j];
            float w2v = W2s[j];
            #pragma unroll
            for (int m = 0; m < 2; m++)
                #pragma unroll
                for (int r = 0; r < 4; r++) {
                    float hh = fmaxf(acc[m][t][r] + b1v, 0.f);
                    pm[m][r] += hh * w2v;
                }
        }
    }

    // reduce over the 16 cols (lanes quad*16 .. quad*16+15)
    #pragma unroll
    for (int m = 0; m < 2; m++)
        #pragma unroll
        for (int r = 0; r < 4; r++) {
            float p = pm[m][r];
            p += __shfl_xor(p, 1);
            p += __shfl_xor(p, 2);
            p += __shfl_xor(p, 4);
            p += __shfl_xor(p, 8);
            pm[m][r] = p;
        }

    if (col == 0) {
        #pragma unroll
        for (int m = 0; m < 2; m++)
            #pragma unroll
            for (int r = 0; r < 4; r++) {
                float x  = pm[m][r] + b2v;
                float sp = fmaxf(x, 0.f) + log1pf(expf(-fabsf(x)));  // softplus
                float alpha = -expm1f(-sp);                          // 1 - exp(-sp)
                long row = rowbase + m * 16 + quad * 4 + r;          // = 2n + b
                out[(row & 1) * (long)NB + (row >> 1)] = alpha;
            }
    }
}

extern "C" void kernel_launch(void* const* d_in, const int* in_sizes, int n_in,
                              void* d_out, int out_size, void* d_ws, size_t ws_size,
                              hipStream_t stream) {
    const float* imgs   = (const float*)d_in[0];
    const float* feats  = (const float*)d_in[1];
    const float* grid   = (const float*)d_in[2];
    const float* points = (const float*)d_in[3];
    const float* W1     = (const float*)d_in[4];
    const float* b1     = (const float*)d_in[5];
    const float* W2     = (const float*)d_in[6];
    const float* b2     = (const float*)d_in[7];
    float* out = (float*)d_out;

    // workspace: imgsP(u8) 10.49MB | featsP 10.49MB | Bfrag 48KB | bw 2.05KB
    uint2*          imgsP  = (uint2*)d_ws;
    unsigned short* featsP = (unsigned short*)(imgsP + (size_t)NVIEW * IMG_HW);
    unsigned int*   Bfrag  = (unsigned int*)(featsP + (size_t)NVIEW * FT_HW * 64);
    float*          bwbuf  = (float*)(Bfrag + 12288);

    prep<<<dim3(2608), dim3(256), 0, stream>>>(
        imgs, feats, W1, b1, W2, b2,
        imgsP, (uint4*)featsP, Bfrag, bwbuf);
    fused_gather_mlp<<<dim3(2000), dim3(256), 0, stream>>>(
        imgsP, featsP, grid, points, Bfrag, bwbuf, out);
}